// Round 10
// baseline (324.670 us; speedup 1.0000x reference)
//
#include <hip/hip_runtime.h>
#include <math.h>

#define LWT 512
#define NWT 64
#define BB 4
#define SBASE 16

// ws layout (floats): sarr [0,BT) level-0 local scans | idx [BT,2BT) | wtT [2BT,+32768)

// XLA algsimp: x / 44100 -> x * RN32(1/44100); the subsequent *512 folds into
// the constant exactly (power-of-2 scaling commutes with rounding), so
// increment = RN32(p * C), C = RN32(512/44100).
#define INC_C ((float)(512.0 / 44100.0))

// The asm barrier forces the product to be ROUNDED to f32 before use --
// without it, -ffp-contract=fast fuses the multiply into the consuming
// add/sub (v_fmac_f32) and the product is never rounded (r9's probe bug).
__device__ __forceinline__ float inc_of(const float* p, int t) {
  float v = p[t] * INC_C;
  asm volatile("" : "+v"(v));
  return v;
}

// Base-16 recursive blocked scan (XLA ReduceWindowRewriter; coarse DAG
// validated by r7's 82%-variance-share): per-16-block sequential local scans;
// block totals = last local element (slice, NOT a tree reduce -- r8 disproved
// trees); totals scanned recursively; one combine add per element per level
// (block 0 adds +0.0 = bit-exact identity). Pads-to-16 are exact zero adds.
// T=132300: 132300 -> 8269 -> 517 -> 33 -> 3 (seq).
__global__ void __launch_bounds__(1024) blocked_scan(const float* __restrict__ pitch,
                                                     float* __restrict__ sarr,
                                                     float* __restrict__ idx, int T) {
  int b = blockIdx.x;
  int tid = threadIdx.x;
  const float* prow = pitch + (size_t)b * T;
  __shared__ float s1[8320];  // NB1 <= 8269
  __shared__ float s2[544];   // NB2 <= 517
  __shared__ float s3[48];    // NB3 <= 33
  __shared__ float s4[16];    // NB4 <= 3
  const int NB1 = (T + SBASE - 1) / SBASE;
  const int NB2 = (NB1 + SBASE - 1) / SBASE;
  const int NB3 = (NB2 + SBASE - 1) / SBASE;
  const int NB4 = (NB3 + SBASE - 1) / SBASE;

  // level 0: per-block sequential local scans -> sarr; totals (last elem) -> s1
  for (int k = tid; k < NB1; k += 1024) {
    int t0 = k * SBASE, t1 = t0 + SBASE < T ? t0 + SBASE : T;
    float run = 0.0f;
    for (int t = t0; t < t1; ++t) { run += inc_of(prow, t); sarr[(size_t)b * T + t] = run; }
    s1[k] = run;
  }
  __syncthreads();
  // level 1: local scans of s1 in place; totals -> s2
  for (int k = tid; k < NB2; k += 1024) {
    int a0 = k * SBASE, a1 = a0 + SBASE < NB1 ? a0 + SBASE : NB1;
    float run = 0.0f;
    for (int a = a0; a < a1; ++a) { run += s1[a]; s1[a] = run; }
    s2[k] = run;
  }
  __syncthreads();
  // level 2: local scans of s2 in place; totals -> s3
  for (int k = tid; k < NB3; k += 1024) {
    int a0 = k * SBASE, a1 = a0 + SBASE < NB2 ? a0 + SBASE : NB2;
    float run = 0.0f;
    for (int a = a0; a < a1; ++a) { run += s2[a]; s2[a] = run; }
    s3[k] = run;
  }
  __syncthreads();
  // level 3: local scans of s3 in place; totals -> s4
  for (int k = tid; k < NB4; k += 1024) {
    int a0 = k * SBASE, a1 = a0 + SBASE < NB3 ? a0 + SBASE : NB3;
    float run = 0.0f;
    for (int a = a0; a < a1; ++a) { run += s3[a]; s3[a] = run; }
    s4[k] = run;
  }
  __syncthreads();
  // level 4: NB4 <= 16 -> plain sequential scan
  if (tid == 0) { float r = 0.0f; for (int a = 0; a < NB4; ++a) { r += s4[a]; s4[a] = r; } }
  __syncthreads();
  // combine: s3 += scanned s4[k-1]
  for (int a = tid; a < NB3; a += 1024)
    if (a >= SBASE) s3[a] = s3[a] + s4[a / SBASE - 1];
  __syncthreads();
  // combine: s2 += scanned s3[k-1]
  for (int a = tid; a < NB2; a += 1024)
    if (a >= SBASE) s2[a] = s2[a] + s3[a / SBASE - 1];
  __syncthreads();
  // combine: s1 += scanned s2[k-1]
  for (int a = tid; a < NB1; a += 1024)
    if (a >= SBASE) s1[a] = s1[a] + s2[a / SBASE - 1];
  __syncthreads();

  // final: S = local0 + scanned1[k-1]; index = (S - inc_row0) mod 512
  for (int t = tid; t < T; t += 1024) {
    float S = sarr[(size_t)b * T + t];
    if (t >= SBASE) S = S + s1[t / SBASE - 1];
    float iv = S - inc_of(pitch, t);  // row-0 increment, same folded constant
    iv = fmodf(iv, 512.0f);
    if (iv < 0.0f) iv += 512.0f;
    idx[(size_t)b * T + t] = iv;
  }
}

__global__ void transpose_wt(const float* __restrict__ wt, float* __restrict__ wtT) {
  int i = blockIdx.x * blockDim.x + threadIdx.x;
  if (i < NWT * LWT) {
    int n = i >> 9, c = i & 511;
    wtT[c * NWT + n] = wt[i];
  }
}

// idx f32 in [0,512]; floor/ceil/alpha (alpha exact via Sterbenz). il clips at
// 511 (jnp.take clip); ih = (int)ceil % 512 (512 wraps to 0); wt[:,511]==wt[:,0].
__device__ __forceinline__ void calc_idx(float idxv, int& il, int& ih, float& alpha) {
  float fl = floorf(idxv);
  alpha = idxv - fl;
  int ili = (int)fl;
  il = ili > 511 ? 511 : ili;
  ih = ((int)ceilf(idxv)) & 511;
}

// One wave per output t. Phase 1: att_pre[t0-2 .. t0+65] into LDS (conv halo,
// zero-padded). Phase 2: conv5 + lane-softmax over 64 wavetables + per-batch
// dot(waveform, att) + amplitude.
__global__ void __launch_bounds__(256) fused_out(
    const float* __restrict__ idx, const float* __restrict__ y,
    const float* __restrict__ amp, const float* __restrict__ wtT,
    const float* __restrict__ cw, const float* __restrict__ cb,
    float* __restrict__ out, int T) {
  __shared__ float lds_att[68][64];
  int t0 = blockIdx.x * 64;
  int wid = threadIdx.x >> 6, lane = threadIdx.x & 63;

  for (int i = wid; i < 68; i += 4) {
    int t = t0 - 2 + i;
    float acc = 0.0f;
    if (t >= 0 && t < T) {
      for (int b = 0; b < BB; ++b) {
        int il, ih; float alpha;
        calc_idx(idx[(size_t)b * T + t], il, ih, alpha);
        float lo = wtT[il * NWT + lane];
        float hi = wtT[ih * NWT + lane];
        acc += (lo + alpha * (hi - lo)) * y[(size_t)b * T + t];
      }
      acc *= 0.25f;  // mean over batch
    }
    lds_att[i][lane] = acc;
  }
  __syncthreads();

  float w0 = cw[0], w1 = cw[1], w2 = cw[2], w3 = cw[3], w4 = cw[4];
  float bias = cb[0];
  for (int i = wid; i < 64; i += 4) {
    int t = t0 + i;
    if (t >= T) continue;  // wave-uniform
    float c = bias + lds_att[i][lane] * w0 + lds_att[i + 1][lane] * w1 +
              lds_att[i + 2][lane] * w2 + lds_att[i + 3][lane] * w3 +
              lds_att[i + 4][lane] * w4;
    // softmax across the 64 lanes (wavetable axis)
    float m = c;
    for (int o = 32; o >= 1; o >>= 1) m = fmaxf(m, __shfl_xor(m, o));
    float e = expf(c - m);
    float ssum = e;
    for (int o = 32; o >= 1; o >>= 1) ssum += __shfl_xor(ssum, o);
    float a = e / ssum;
    // out[b,t] = amp[b,t] * sum_n waveforms[n,b,t] * att[n,t]
    for (int b = 0; b < BB; ++b) {
      int il, ih; float alpha;
      calc_idx(idx[(size_t)b * T + t], il, ih, alpha);
      float lo = wtT[il * NWT + lane];
      float hi = wtT[ih * NWT + lane];
      float wv = lo + alpha * (hi - lo);
      float p = a * wv;
      for (int o = 32; o >= 1; o >>= 1) p += __shfl_xor(p, o);
      if (lane == 0) out[(size_t)b * T + t] = p * amp[(size_t)b * T + t];
    }
  }
}

extern "C" void kernel_launch(void* const* d_in, const int* in_sizes, int n_in,
                              void* d_out, int out_size, void* d_ws, size_t ws_size,
                              hipStream_t stream) {
  const float* pitch = (const float*)d_in[0];
  const float* amp   = (const float*)d_in[1];
  const float* y     = (const float*)d_in[2];
  const float* wt    = (const float*)d_in[3];
  const float* cw    = (const float*)d_in[4];
  const float* cb    = (const float*)d_in[5];
  float* out = (float*)d_out;

  int BT = in_sizes[2];   // B*T
  int T = BT / BB;        // 132300

  float* ws   = (float*)d_ws;
  float* sarr = ws;
  float* idx  = ws + (size_t)BT;
  float* wtT  = ws + (size_t)2 * BT;

  hipLaunchKernelGGL(blocked_scan, dim3(BB), dim3(1024), 0, stream, pitch, sarr, idx, T);
  hipLaunchKernelGGL(transpose_wt, dim3((NWT * LWT + 255) / 256), dim3(256), 0, stream, wt, wtT);
  hipLaunchKernelGGL(fused_out, dim3((T + 63) / 64), dim3(256), 0, stream,
                     idx, y, amp, wtT, cw, cb, out, T);
}

// Round 11
// 128.024 us; speedup vs baseline: 2.5360x; 2.5360x over previous
//
#include <hip/hip_runtime.h>
#include <math.h>

#define LWT 512
#define NWT 64
#define BB 4
#define SBASE 16

// ws layout (floats): sarr [0,BT) | idx [BT,2BT) | wtT [2BT,+32768) | s1g [.., +4*8320)

// XLA algsimp: x/44100 -> x * RN32(1/44100); *512 folds exactly (pow2), so
// increment = RN32(p * C), C = RN32(512/44100). asm barrier forces the product
// to be ROUNDED before the consuming add (blocks -ffp-contract=fast fusion).
#define INC_C ((float)(512.0 / 44100.0))

__device__ __forceinline__ float inc_mul(float p) {
  float v = p * INC_C;
  asm volatile("" : "+v"(v));
  return v;
}
__device__ __forceinline__ float inc_of(const float* p, int t) { return inc_mul(p[t]); }

// ---- Kernel A: level-0 local scans (fully parallel over 16-blocks) ----
// Per 16-block: sequential f32 local prefix -> sarr; total (= last) -> s1g.
// Bit-identical op order to the r10-passing monolithic kernel.
__global__ void __launch_bounds__(256) scan_level0(const float* __restrict__ pitch,
                                                   float* __restrict__ sarr,
                                                   float* __restrict__ s1g,
                                                   int T, int NB1) {
  int k = blockIdx.x * blockDim.x + threadIdx.x;
  int b = blockIdx.y;
  if (k >= NB1) return;
  const float* prow = pitch + (size_t)b * T;
  float* srow = sarr + (size_t)b * T;
  int t0 = k * SBASE;
  float run = 0.0f;
  if (t0 + SBASE <= T) {  // full block: float4 I/O
    const float4* p4 = reinterpret_cast<const float4*>(prow + t0);
    float4* s4o = reinterpret_cast<float4*>(srow + t0);
#pragma unroll
    for (int i = 0; i < 4; ++i) {
      float4 v = p4[i];
      float4 o;
      run += inc_mul(v.x); o.x = run;
      run += inc_mul(v.y); o.y = run;
      run += inc_mul(v.z); o.z = run;
      run += inc_mul(v.w); o.w = run;
      s4o[i] = o;
    }
  } else {
    for (int t = t0; t < T; ++t) { run += inc_of(prow, t); srow[t] = run; }
  }
  s1g[(size_t)b * NB1 + k] = run;
}

// ---- Kernel B: levels 1..4 + combines, per row, s1 in LDS ----
// Identical op order to r10: local 16-scans of s1 -> totals s2; s2 -> s3;
// s3 -> s4; s4 sequential; combines s3+=s4[k-1], s2+=s3[k-1], s1+=s2[k-1].
// Writes back fully-scanned s1.
__global__ void __launch_bounds__(1024) scan_upper(float* __restrict__ s1g, int NB1) {
  int b = blockIdx.x;
  int tid = threadIdx.x;
  float* s1r = s1g + (size_t)b * NB1;
  __shared__ float s1[8320];
  __shared__ float s2[544];
  __shared__ float s3[48];
  __shared__ float s4[16];
  const int NB2 = (NB1 + SBASE - 1) / SBASE;
  const int NB3 = (NB2 + SBASE - 1) / SBASE;
  const int NB4 = (NB3 + SBASE - 1) / SBASE;

  for (int a = tid; a < NB1; a += 1024) s1[a] = s1r[a];
  __syncthreads();
  // level 1
  for (int k = tid; k < NB2; k += 1024) {
    int a0 = k * SBASE, a1 = a0 + SBASE < NB1 ? a0 + SBASE : NB1;
    float run = 0.0f;
    for (int a = a0; a < a1; ++a) { run += s1[a]; s1[a] = run; }
    s2[k] = run;
  }
  __syncthreads();
  // level 2
  for (int k = tid; k < NB3; k += 1024) {
    int a0 = k * SBASE, a1 = a0 + SBASE < NB2 ? a0 + SBASE : NB2;
    float run = 0.0f;
    for (int a = a0; a < a1; ++a) { run += s2[a]; s2[a] = run; }
    s3[k] = run;
  }
  __syncthreads();
  // level 3
  for (int k = tid; k < NB4; k += 1024) {
    int a0 = k * SBASE, a1 = a0 + SBASE < NB3 ? a0 + SBASE : NB3;
    float run = 0.0f;
    for (int a = a0; a < a1; ++a) { run += s3[a]; s3[a] = run; }
    s4[k] = run;
  }
  __syncthreads();
  // level 4 (NB4 <= 16)
  if (tid == 0) { float r = 0.0f; for (int a = 0; a < NB4; ++a) { r += s4[a]; s4[a] = r; } }
  __syncthreads();
  for (int a = tid; a < NB3; a += 1024)
    if (a >= SBASE) s3[a] = s3[a] + s4[a / SBASE - 1];
  __syncthreads();
  for (int a = tid; a < NB2; a += 1024)
    if (a >= SBASE) s2[a] = s2[a] + s3[a / SBASE - 1];
  __syncthreads();
  for (int a = tid; a < NB1; a += 1024) {
    float v = s1[a];
    if (a >= SBASE) v = v + s2[a / SBASE - 1];
    s1r[a] = v;
  }
}

// ---- Kernel C: final combine + mod (fully parallel) ----
__global__ void __launch_bounds__(256) finalize_idx(const float* __restrict__ pitch,
                                                    const float* __restrict__ sarr,
                                                    const float* __restrict__ s1g,
                                                    float* __restrict__ idx,
                                                    int T, int NB1) {
  int t = blockIdx.x * blockDim.x + threadIdx.x;
  int b = blockIdx.y;
  if (t >= T) return;
  float S = sarr[(size_t)b * T + t];
  if (t >= SBASE) S = S + s1g[(size_t)b * NB1 + t / SBASE - 1];
  float iv = S - inc_of(pitch, t);  // row-0 increment, same folded constant
  iv = fmodf(iv, 512.0f);
  if (iv < 0.0f) iv += 512.0f;
  idx[(size_t)b * T + t] = iv;
}

__global__ void transpose_wt(const float* __restrict__ wt, float* __restrict__ wtT) {
  int i = blockIdx.x * blockDim.x + threadIdx.x;
  if (i < NWT * LWT) {
    int n = i >> 9, c = i & 511;
    wtT[c * NWT + n] = wt[i];
  }
}

// idx f32 in [0,512]; floor/ceil/alpha (alpha exact via Sterbenz). il clips at
// 511 (jnp.take clip); ih = (int)ceil % 512 (512 wraps to 0); wt[:,511]==wt[:,0].
__device__ __forceinline__ void calc_idx(float idxv, int& il, int& ih, float& alpha) {
  float fl = floorf(idxv);
  alpha = idxv - fl;
  int ili = (int)fl;
  il = ili > 511 ? 511 : ili;
  ih = ((int)ceilf(idxv)) & 511;
}

// One wave per output t. Phase 1: att_pre[t0-2 .. t0+65] into LDS (conv halo,
// zero-padded). Phase 2: conv5 + lane-softmax over 64 wavetables + per-batch
// dot(waveform, att) + amplitude.
__global__ void __launch_bounds__(256) fused_out(
    const float* __restrict__ idx, const float* __restrict__ y,
    const float* __restrict__ amp, const float* __restrict__ wtT,
    const float* __restrict__ cw, const float* __restrict__ cb,
    float* __restrict__ out, int T) {
  __shared__ float lds_att[68][64];
  int t0 = blockIdx.x * 64;
  int wid = threadIdx.x >> 6, lane = threadIdx.x & 63;

  for (int i = wid; i < 68; i += 4) {
    int t = t0 - 2 + i;
    float acc = 0.0f;
    if (t >= 0 && t < T) {
      for (int b = 0; b < BB; ++b) {
        int il, ih; float alpha;
        calc_idx(idx[(size_t)b * T + t], il, ih, alpha);
        float lo = wtT[il * NWT + lane];
        float hi = wtT[ih * NWT + lane];
        acc += (lo + alpha * (hi - lo)) * y[(size_t)b * T + t];
      }
      acc *= 0.25f;  // mean over batch
    }
    lds_att[i][lane] = acc;
  }
  __syncthreads();

  float w0 = cw[0], w1 = cw[1], w2 = cw[2], w3 = cw[3], w4 = cw[4];
  float bias = cb[0];
  for (int i = wid; i < 64; i += 4) {
    int t = t0 + i;
    if (t >= T) continue;  // wave-uniform
    float c = bias + lds_att[i][lane] * w0 + lds_att[i + 1][lane] * w1 +
              lds_att[i + 2][lane] * w2 + lds_att[i + 3][lane] * w3 +
              lds_att[i + 4][lane] * w4;
    // softmax across the 64 lanes (wavetable axis)
    float m = c;
    for (int o = 32; o >= 1; o >>= 1) m = fmaxf(m, __shfl_xor(m, o));
    float e = expf(c - m);
    float ssum = e;
    for (int o = 32; o >= 1; o >>= 1) ssum += __shfl_xor(ssum, o);
    float a = e / ssum;
    // out[b,t] = amp[b,t] * sum_n waveforms[n,b,t] * att[n,t]
    for (int b = 0; b < BB; ++b) {
      int il, ih; float alpha;
      calc_idx(idx[(size_t)b * T + t], il, ih, alpha);
      float lo = wtT[il * NWT + lane];
      float hi = wtT[ih * NWT + lane];
      float wv = lo + alpha * (hi - lo);
      float p = a * wv;
      for (int o = 32; o >= 1; o >>= 1) p += __shfl_xor(p, o);
      if (lane == 0) out[(size_t)b * T + t] = p * amp[(size_t)b * T + t];
    }
  }
}

extern "C" void kernel_launch(void* const* d_in, const int* in_sizes, int n_in,
                              void* d_out, int out_size, void* d_ws, size_t ws_size,
                              hipStream_t stream) {
  const float* pitch = (const float*)d_in[0];
  const float* amp   = (const float*)d_in[1];
  const float* y     = (const float*)d_in[2];
  const float* wt    = (const float*)d_in[3];
  const float* cw    = (const float*)d_in[4];
  const float* cb    = (const float*)d_in[5];
  float* out = (float*)d_out;

  int BT = in_sizes[2];   // B*T
  int T = BT / BB;        // 132300
  int NB1 = (T + SBASE - 1) / SBASE;  // 8269

  float* ws   = (float*)d_ws;
  float* sarr = ws;
  float* idx  = ws + (size_t)BT;
  float* wtT  = ws + (size_t)2 * BT;
  float* s1g  = ws + (size_t)2 * BT + NWT * LWT;

  hipLaunchKernelGGL(scan_level0, dim3((NB1 + 255) / 256, BB), dim3(256), 0, stream,
                     pitch, sarr, s1g, T, NB1);
  hipLaunchKernelGGL(scan_upper, dim3(BB), dim3(1024), 0, stream, s1g, NB1);
  hipLaunchKernelGGL(finalize_idx, dim3((T + 255) / 256, BB), dim3(256), 0, stream,
                     pitch, sarr, s1g, idx, T, NB1);
  hipLaunchKernelGGL(transpose_wt, dim3((NWT * LWT + 255) / 256), dim3(256), 0, stream, wt, wtT);
  hipLaunchKernelGGL(fused_out, dim3((T + 63) / 64), dim3(256), 0, stream,
                     idx, y, amp, wtT, cw, cb, out, T);
}

// Round 12
// 93.508 us; speedup vs baseline: 3.4721x; 1.3691x over previous
//
#include <hip/hip_runtime.h>
#include <math.h>

#define LWT 512
#define NWT 64
#define BB 4
#define SBASE 16

// ws layout (floats): sarr [0,BT) | wtT [+32768) | s1g [+4*8320)

// XLA algsimp: x/44100 -> x * RN32(1/44100); *512 folds exactly (pow2), so
// increment = RN32(p * C), C = RN32(512/44100). asm barrier forces the product
// to be ROUNDED before the consuming add (blocks -ffp-contract=fast fusion).
#define INC_C ((float)(512.0 / 44100.0))

__device__ __forceinline__ float inc_mul(float p) {
  float v = p * INC_C;
  asm volatile("" : "+v"(v));
  return v;
}
__device__ __forceinline__ float inc_of(const float* p, int t) { return inc_mul(p[t]); }

// ---- Kernel A: level-0 local scans (fully parallel over 16-blocks) ----
__global__ void __launch_bounds__(256) scan_level0(const float* __restrict__ pitch,
                                                   float* __restrict__ sarr,
                                                   float* __restrict__ s1g,
                                                   int T, int NB1) {
  int k = blockIdx.x * blockDim.x + threadIdx.x;
  int b = blockIdx.y;
  if (k >= NB1) return;
  const float* prow = pitch + (size_t)b * T;
  float* srow = sarr + (size_t)b * T;
  int t0 = k * SBASE;
  float run = 0.0f;
  if (t0 + SBASE <= T) {
    const float4* p4 = reinterpret_cast<const float4*>(prow + t0);
    float4* s4o = reinterpret_cast<float4*>(srow + t0);
#pragma unroll
    for (int i = 0; i < 4; ++i) {
      float4 v = p4[i];
      float4 o;
      run += inc_mul(v.x); o.x = run;
      run += inc_mul(v.y); o.y = run;
      run += inc_mul(v.z); o.z = run;
      run += inc_mul(v.w); o.w = run;
      s4o[i] = o;
    }
  } else {
    for (int t = t0; t < T; ++t) { run += inc_of(prow, t); srow[t] = run; }
  }
  s1g[(size_t)b * NB1 + k] = run;
}

// ---- Kernel B: levels 1..4 + combines, per row, s1 in LDS ----
__global__ void __launch_bounds__(1024) scan_upper(float* __restrict__ s1g, int NB1) {
  int b = blockIdx.x;
  int tid = threadIdx.x;
  float* s1r = s1g + (size_t)b * NB1;
  __shared__ float s1[8320];
  __shared__ float s2[544];
  __shared__ float s3[48];
  __shared__ float s4[16];
  const int NB2 = (NB1 + SBASE - 1) / SBASE;
  const int NB3 = (NB2 + SBASE - 1) / SBASE;
  const int NB4 = (NB3 + SBASE - 1) / SBASE;

  for (int a = tid; a < NB1; a += 1024) s1[a] = s1r[a];
  __syncthreads();
  for (int k = tid; k < NB2; k += 1024) {
    int a0 = k * SBASE, a1 = a0 + SBASE < NB1 ? a0 + SBASE : NB1;
    float run = 0.0f;
    for (int a = a0; a < a1; ++a) { run += s1[a]; s1[a] = run; }
    s2[k] = run;
  }
  __syncthreads();
  for (int k = tid; k < NB3; k += 1024) {
    int a0 = k * SBASE, a1 = a0 + SBASE < NB2 ? a0 + SBASE : NB2;
    float run = 0.0f;
    for (int a = a0; a < a1; ++a) { run += s2[a]; s2[a] = run; }
    s3[k] = run;
  }
  __syncthreads();
  for (int k = tid; k < NB4; k += 1024) {
    int a0 = k * SBASE, a1 = a0 + SBASE < NB3 ? a0 + SBASE : NB3;
    float run = 0.0f;
    for (int a = a0; a < a1; ++a) { run += s3[a]; s3[a] = run; }
    s4[k] = run;
  }
  __syncthreads();
  if (tid == 0) { float r = 0.0f; for (int a = 0; a < NB4; ++a) { r += s4[a]; s4[a] = r; } }
  __syncthreads();
  for (int a = tid; a < NB3; a += 1024)
    if (a >= SBASE) s3[a] = s3[a] + s4[a / SBASE - 1];
  __syncthreads();
  for (int a = tid; a < NB2; a += 1024)
    if (a >= SBASE) s2[a] = s2[a] + s3[a / SBASE - 1];
  __syncthreads();
  for (int a = tid; a < NB1; a += 1024) {
    float v = s1[a];
    if (a >= SBASE) v = v + s2[a / SBASE - 1];
    s1r[a] = v;
  }
}

__global__ void transpose_wt(const float* __restrict__ wt, float* __restrict__ wtT) {
  int i = blockIdx.x * blockDim.x + threadIdx.x;
  if (i < NWT * LWT) {
    int n = i >> 9, c = i & 511;
    wtT[c * NWT + n] = wt[i];
  }
}

// ---- Fused: finalize(idx) + att_pre + conv + softmax + einsum + amp ----
// Phase 1: lanes 0..3 compute per-batch (il,ih,alpha) ONCE (bit-identical to
// the r10 fmodf path: iv*2^-9 exact, floorf exact, one fmaf rounding), stage
// in LDS; all lanes accumulate att_pre. Phase 2: conv5 + exp (max-subtract
// dropped: softmax is shift-invariant; out perturbation ~1e-9 vs 7.7e-5
// budget) + 5 fused xor-tree reductions (ssum + 4 einsums) + rcp + amp.
__global__ void __launch_bounds__(256) fused_out(
    const float* __restrict__ pitch, const float* __restrict__ sarr,
    const float* __restrict__ s1g, const float* __restrict__ y,
    const float* __restrict__ amp, const float* __restrict__ wtT,
    const float* __restrict__ cw, const float* __restrict__ cb,
    float* __restrict__ out, int T, int NB1) {
  __shared__ float lds_att[68][64];
  __shared__ uint2 lds_stage[68][4];  // .x = il | ih<<16, .y = bits(alpha)
  int t0 = blockIdx.x * 64;
  int wid = threadIdx.x >> 6, lane = threadIdx.x & 63;

  for (int i = wid; i < 68; i += 4) {
    int t = t0 - 2 + i;
    float acc = 0.0f;
    if (t >= 0 && t < T) {
      if (lane < BB) {
        int b = lane;
        float S = sarr[b * T + t];
        if (t >= SBASE) S = S + s1g[b * NB1 + (t >> 4) - 1];
        float iv = S - inc_of(pitch, t);   // row-0 increment, folded constant
        // exact mod 512: q exact (pow2 scale), k = true floor, single rounding
        float q = iv * (1.0f / 512.0f);
        float k = floorf(q);
        iv = fmaf(-k, 512.0f, iv);          // == fmodf+fixup bits in all cases
        float fl = floorf(iv);
        float alpha = iv - fl;              // exact (Sterbenz)
        int ili = (int)fl; if (ili > 511) ili = 511;   // jnp.take clip at 512.0
        int ihi = ((int)ceilf(iv)) & 511;              // ceil 512 wraps to 0
        uint2 st;
        st.x = (unsigned)ili | ((unsigned)ihi << 16);
        st.y = __float_as_uint(alpha);
        lds_stage[i][b] = st;
      }
      // same-wave LDS write->read: compiler orders via lgkmcnt, no barrier
#pragma unroll
      for (int b = 0; b < BB; ++b) {
        uint2 st = lds_stage[i][b];
        int ili = st.x & 0xffff, ihi = st.x >> 16;
        float alpha = __uint_as_float(st.y);
        float lo = wtT[ili * NWT + lane];
        float hi = wtT[ihi * NWT + lane];
        acc += (lo + alpha * (hi - lo)) * y[b * T + t];
      }
      acc *= 0.25f;  // mean over batch
    }
    lds_att[i][lane] = acc;
  }
  __syncthreads();

  float w0 = cw[0], w1 = cw[1], w2 = cw[2], w3 = cw[3], w4 = cw[4];
  float bias = cb[0];
#pragma unroll 2
  for (int i = wid; i < 64; i += 4) {
    int t = t0 + i;
    if (t >= T) continue;  // wave-uniform
    float c = bias + lds_att[i][lane] * w0 + lds_att[i + 1][lane] * w1 +
              lds_att[i + 2][lane] * w2 + lds_att[i + 3][lane] * w3 +
              lds_att[i + 4][lane] * w4;
    float e = __expf(c);   // no max-subtract (shift-invariant, c bounded)
    float r0, r1, r2, r3, r4;
    {
      uint2 st = lds_stage[i + 2][0];
      int ili = st.x & 0xffff, ihi = st.x >> 16;
      float alpha = __uint_as_float(st.y);
      float lo = wtT[ili * NWT + lane], hi = wtT[ihi * NWT + lane];
      r0 = e * (lo + alpha * (hi - lo));
    }
    {
      uint2 st = lds_stage[i + 2][1];
      int ili = st.x & 0xffff, ihi = st.x >> 16;
      float alpha = __uint_as_float(st.y);
      float lo = wtT[ili * NWT + lane], hi = wtT[ihi * NWT + lane];
      r1 = e * (lo + alpha * (hi - lo));
    }
    {
      uint2 st = lds_stage[i + 2][2];
      int ili = st.x & 0xffff, ihi = st.x >> 16;
      float alpha = __uint_as_float(st.y);
      float lo = wtT[ili * NWT + lane], hi = wtT[ihi * NWT + lane];
      r2 = e * (lo + alpha * (hi - lo));
    }
    {
      uint2 st = lds_stage[i + 2][3];
      int ili = st.x & 0xffff, ihi = st.x >> 16;
      float alpha = __uint_as_float(st.y);
      float lo = wtT[ili * NWT + lane], hi = wtT[ihi * NWT + lane];
      r3 = e * (lo + alpha * (hi - lo));
    }
    r4 = e;
    // 5 interleaved butterfly reductions (ILP across independent chains)
#pragma unroll
    for (int o = 32; o >= 1; o >>= 1) {
      r0 += __shfl_xor(r0, o);
      r1 += __shfl_xor(r1, o);
      r2 += __shfl_xor(r2, o);
      r3 += __shfl_xor(r3, o);
      r4 += __shfl_xor(r4, o);
    }
    if (lane < BB) {
      float pv = lane == 0 ? r0 : lane == 1 ? r1 : lane == 2 ? r2 : r3;
#if __has_builtin(__builtin_amdgcn_rcpf)
      float rc = __builtin_amdgcn_rcpf(r4);
#else
      float rc = 1.0f / r4;
#endif
      out[lane * T + t] = pv * rc * amp[lane * T + t];
    }
  }
}

extern "C" void kernel_launch(void* const* d_in, const int* in_sizes, int n_in,
                              void* d_out, int out_size, void* d_ws, size_t ws_size,
                              hipStream_t stream) {
  const float* pitch = (const float*)d_in[0];
  const float* amp   = (const float*)d_in[1];
  const float* y     = (const float*)d_in[2];
  const float* wt    = (const float*)d_in[3];
  const float* cw    = (const float*)d_in[4];
  const float* cb    = (const float*)d_in[5];
  float* out = (float*)d_out;

  int BT = in_sizes[2];   // B*T
  int T = BT / BB;        // 132300
  int NB1 = (T + SBASE - 1) / SBASE;  // 8269

  float* ws   = (float*)d_ws;
  float* sarr = ws;
  float* wtT  = ws + (size_t)BT;
  float* s1g  = ws + (size_t)BT + NWT * LWT;

  hipLaunchKernelGGL(scan_level0, dim3((NB1 + 255) / 256, BB), dim3(256), 0, stream,
                     pitch, sarr, s1g, T, NB1);
  hipLaunchKernelGGL(scan_upper, dim3(BB), dim3(1024), 0, stream, s1g, NB1);
  hipLaunchKernelGGL(transpose_wt, dim3((NWT * LWT + 255) / 256), dim3(256), 0, stream, wt, wtT);
  hipLaunchKernelGGL(fused_out, dim3((T + 63) / 64), dim3(256), 0, stream,
                     pitch, sarr, s1g, y, amp, wtT, cw, cb, out, T, NB1);
}

// Round 13
// 61.792 us; speedup vs baseline: 5.2543x; 1.5133x over previous
//
#include <hip/hip_runtime.h>
#include <math.h>

#define LWT 512
#define NWT 64
#define BB 4
#define SBASE 16

// ws layout (floats): sarr [0,BT) | wtT [+32768) | s1g [+4*8320)

// XLA algsimp: x/44100 -> x * RN32(1/44100); *512 folds exactly (pow2), so
// increment = RN32(p * C), C = RN32(512/44100). asm barrier forces the product
// to be ROUNDED before the consuming add (blocks -ffp-contract=fast fusion).
#define INC_C ((float)(512.0 / 44100.0))

__device__ __forceinline__ float inc_mul(float p) {
  float v = p * INC_C;
  asm volatile("" : "+v"(v));
  return v;
}
__device__ __forceinline__ float inc_of(const float* p, int t) { return inc_mul(p[t]); }

// ---- Kernel A: level-0 local scans (fully parallel over 16-blocks) ----
__global__ void __launch_bounds__(256) scan_level0(const float* __restrict__ pitch,
                                                   float* __restrict__ sarr,
                                                   float* __restrict__ s1g,
                                                   int T, int NB1) {
  int k = blockIdx.x * blockDim.x + threadIdx.x;
  int b = blockIdx.y;
  if (k >= NB1) return;
  const float* prow = pitch + (size_t)b * T;
  float* srow = sarr + (size_t)b * T;
  int t0 = k * SBASE;
  float run = 0.0f;
  if (t0 + SBASE <= T) {
    const float4* p4 = reinterpret_cast<const float4*>(prow + t0);
    float4* s4o = reinterpret_cast<float4*>(srow + t0);
#pragma unroll
    for (int i = 0; i < 4; ++i) {
      float4 v = p4[i];
      float4 o;
      run += inc_mul(v.x); o.x = run;
      run += inc_mul(v.y); o.y = run;
      run += inc_mul(v.z); o.z = run;
      run += inc_mul(v.w); o.w = run;
      s4o[i] = o;
    }
  } else {
    for (int t = t0; t < T; ++t) { run += inc_of(prow, t); srow[t] = run; }
  }
  s1g[(size_t)b * NB1 + k] = run;
}

// ---- Kernel B: levels 1..4 + combines, per row, s1 in LDS ----
__global__ void __launch_bounds__(1024) scan_upper(float* __restrict__ s1g, int NB1) {
  int b = blockIdx.x;
  int tid = threadIdx.x;
  float* s1r = s1g + (size_t)b * NB1;
  __shared__ float s1[8320];
  __shared__ float s2[544];
  __shared__ float s3[48];
  __shared__ float s4[16];
  const int NB2 = (NB1 + SBASE - 1) / SBASE;
  const int NB3 = (NB2 + SBASE - 1) / SBASE;
  const int NB4 = (NB3 + SBASE - 1) / SBASE;

  for (int a = tid; a < NB1; a += 1024) s1[a] = s1r[a];
  __syncthreads();
  for (int k = tid; k < NB2; k += 1024) {
    int a0 = k * SBASE, a1 = a0 + SBASE < NB1 ? a0 + SBASE : NB1;
    float run = 0.0f;
    for (int a = a0; a < a1; ++a) { run += s1[a]; s1[a] = run; }
    s2[k] = run;
  }
  __syncthreads();
  for (int k = tid; k < NB3; k += 1024) {
    int a0 = k * SBASE, a1 = a0 + SBASE < NB2 ? a0 + SBASE : NB2;
    float run = 0.0f;
    for (int a = a0; a < a1; ++a) { run += s2[a]; s2[a] = run; }
    s3[k] = run;
  }
  __syncthreads();
  for (int k = tid; k < NB4; k += 1024) {
    int a0 = k * SBASE, a1 = a0 + SBASE < NB3 ? a0 + SBASE : NB3;
    float run = 0.0f;
    for (int a = a0; a < a1; ++a) { run += s3[a]; s3[a] = run; }
    s4[k] = run;
  }
  __syncthreads();
  if (tid == 0) { float r = 0.0f; for (int a = 0; a < NB4; ++a) { r += s4[a]; s4[a] = r; } }
  __syncthreads();
  for (int a = tid; a < NB3; a += 1024)
    if (a >= SBASE) s3[a] = s3[a] + s4[a / SBASE - 1];
  __syncthreads();
  for (int a = tid; a < NB2; a += 1024)
    if (a >= SBASE) s2[a] = s2[a] + s3[a / SBASE - 1];
  __syncthreads();
  for (int a = tid; a < NB1; a += 1024) {
    float v = s1[a];
    if (a >= SBASE) v = v + s2[a / SBASE - 1];
    s1r[a] = v;
  }
}

__global__ void transpose_wt(const float* __restrict__ wt, float* __restrict__ wtT) {
  int i = blockIdx.x * blockDim.x + threadIdx.x;
  if (i < NWT * LWT) {
    int n = i >> 9, c = i & 511;
    wtT[c * NWT + n] = wt[i];
  }
}

// Wave64 reduction entirely on the VALU pipe (DPP), canonical CDNA pattern:
// xor1, xor2 (quad_perm), 8 (row_half_mirror), 16 (row_mirror), 32
// (bcast15, rows 1&3), 64 (bcast31, rows 2&3); full sum lands in lanes
// 48-63; readlane(63) broadcasts via SGPR. Disabled rows add old=0.
__device__ __forceinline__ float dpp_reduce_add(float x) {
  x += __int_as_float(__builtin_amdgcn_update_dpp(0, __float_as_int(x), 0xB1, 0xf, 0xf, true));
  x += __int_as_float(__builtin_amdgcn_update_dpp(0, __float_as_int(x), 0x4E, 0xf, 0xf, true));
  x += __int_as_float(__builtin_amdgcn_update_dpp(0, __float_as_int(x), 0x141, 0xf, 0xf, true));
  x += __int_as_float(__builtin_amdgcn_update_dpp(0, __float_as_int(x), 0x140, 0xf, 0xf, true));
  x += __int_as_float(__builtin_amdgcn_update_dpp(0, __float_as_int(x), 0x142, 0xa, 0xf, true));
  x += __int_as_float(__builtin_amdgcn_update_dpp(0, __float_as_int(x), 0x143, 0xc, 0xf, true));
  return __int_as_float(__builtin_amdgcn_readlane(__float_as_int(x), 63));
}

// ---- Fused: finalize(idx) + att_pre + conv + softmax + einsum + amp ----
// Stage A (full-wave parallel): wave=batch b, lane=i: (il|ih,alpha) once per
// (i,b) [bit-identical r10 mod path], plus y/amp staged to LDS.
// Stage B: att_pre into LDS. Phase 2: conv5 + exp + 5 DPP reductions +
// rcp + amp into out_lds. Epilogue: coalesced stores.
__global__ void __launch_bounds__(256) fused_out(
    const float* __restrict__ pitch, const float* __restrict__ sarr,
    const float* __restrict__ s1g, const float* __restrict__ y,
    const float* __restrict__ amp, const float* __restrict__ wtT,
    const float* __restrict__ cw, const float* __restrict__ cb,
    float* __restrict__ out, int T, int NB1) {
  __shared__ float lds_att[68][64];
  __shared__ uint2 lds_stage[68][4];   // .x = il | ih<<16, .y = bits(alpha)
  __shared__ float y_lds[68][4];
  __shared__ float amp_lds[68][4];
  __shared__ float out_lds[4][64];
  int t0 = blockIdx.x * 64;
  int wid = threadIdx.x >> 6, lane = threadIdx.x & 63;

  // ---- Stage A ----
  {
    int b = wid;
    for (int i = lane; i < 68; i += 64) {
      int t = t0 - 2 + i;
      if (t >= 0 && t < T) {
        float S = sarr[(size_t)b * T + t];
        if (t >= SBASE) S = S + s1g[b * NB1 + (t >> 4) - 1];
        float iv = S - inc_of(pitch, t);   // row-0 increment, folded constant
        // exact mod 512 (== fmodf+fixup bits; q exact pow2 scale, one fma rnd)
        float q = iv * (1.0f / 512.0f);
        float k = floorf(q);
        iv = fmaf(-k, 512.0f, iv);
        float fl = floorf(iv);
        float alpha = iv - fl;              // exact (Sterbenz)
        int ili = (int)fl; if (ili > 511) ili = 511;   // jnp.take clip
        int ihi = ((int)ceilf(iv)) & 511;              // ceil 512 wraps to 0
        uint2 st;
        st.x = (unsigned)ili | ((unsigned)ihi << 16);
        st.y = __float_as_uint(alpha);
        lds_stage[i][b] = st;
        y_lds[i][b] = y[(size_t)b * T + t];
        amp_lds[i][b] = amp[(size_t)b * T + t];
      }
    }
  }
  __syncthreads();

  // ---- Stage B: att_pre ----
  for (int i = wid; i < 68; i += 4) {
    int t = t0 - 2 + i;
    float acc = 0.0f;
    if (t >= 0 && t < T) {
      const float4 yv = *reinterpret_cast<const float4*>(&y_lds[i][0]);
#pragma unroll
      for (int b = 0; b < BB; ++b) {
        uint2 st = lds_stage[i][b];
        int ili = st.x & 0xffff, ihi = st.x >> 16;
        float alpha = __uint_as_float(st.y);
        float lo = wtT[ili * NWT + lane];
        float hi = wtT[ihi * NWT + lane];
        float yb = b == 0 ? yv.x : b == 1 ? yv.y : b == 2 ? yv.z : yv.w;
        acc += (lo + alpha * (hi - lo)) * yb;
      }
      acc *= 0.25f;  // mean over batch
    }
    lds_att[i][lane] = acc;
  }
  __syncthreads();

  float w0 = cw[0], w1 = cw[1], w2 = cw[2], w3 = cw[3], w4 = cw[4];
  float bias = cb[0];
#pragma unroll 4
  for (int i = wid; i < 64; i += 4) {
    int t = t0 + i;
    if (t >= T) continue;  // wave-uniform
    float c = bias + lds_att[i][lane] * w0 + lds_att[i + 1][lane] * w1 +
              lds_att[i + 2][lane] * w2 + lds_att[i + 3][lane] * w3 +
              lds_att[i + 4][lane] * w4;
    float e = __expf(c);   // no max-subtract (shift-invariant, c bounded)
    float r0, r1, r2, r3;
    {
      uint2 st = lds_stage[i + 2][0];
      int ili = st.x & 0xffff, ihi = st.x >> 16;
      float alpha = __uint_as_float(st.y);
      float lo = wtT[ili * NWT + lane], hi = wtT[ihi * NWT + lane];
      r0 = e * (lo + alpha * (hi - lo));
    }
    {
      uint2 st = lds_stage[i + 2][1];
      int ili = st.x & 0xffff, ihi = st.x >> 16;
      float alpha = __uint_as_float(st.y);
      float lo = wtT[ili * NWT + lane], hi = wtT[ihi * NWT + lane];
      r1 = e * (lo + alpha * (hi - lo));
    }
    {
      uint2 st = lds_stage[i + 2][2];
      int ili = st.x & 0xffff, ihi = st.x >> 16;
      float alpha = __uint_as_float(st.y);
      float lo = wtT[ili * NWT + lane], hi = wtT[ihi * NWT + lane];
      r2 = e * (lo + alpha * (hi - lo));
    }
    {
      uint2 st = lds_stage[i + 2][3];
      int ili = st.x & 0xffff, ihi = st.x >> 16;
      float alpha = __uint_as_float(st.y);
      float lo = wtT[ili * NWT + lane], hi = wtT[ihi * NWT + lane];
      r3 = e * (lo + alpha * (hi - lo));
    }
    // 5 VALU-pipe DPP reductions (independent chains; broadcast results)
    float s0 = dpp_reduce_add(r0);
    float s1_ = dpp_reduce_add(r1);
    float s2_ = dpp_reduce_add(r2);
    float s3_ = dpp_reduce_add(r3);
    float ssum = dpp_reduce_add(e);
#if __has_builtin(__builtin_amdgcn_rcpf)
    float rc = __builtin_amdgcn_rcpf(ssum);
#else
    float rc = 1.0f / ssum;
#endif
    if (lane < BB) {
      float pv = lane == 0 ? s0 : lane == 1 ? s1_ : lane == 2 ? s2_ : s3_;
      out_lds[lane][i] = pv * rc * amp_lds[i + 2][lane];
    }
  }
  __syncthreads();

  // ---- Epilogue: coalesced stores (wave = batch, lane = t offset) ----
  {
    int b = wid;
    int t = t0 + lane;
    if (t < T) out[(size_t)b * T + t] = out_lds[b][lane];
  }
}

extern "C" void kernel_launch(void* const* d_in, const int* in_sizes, int n_in,
                              void* d_out, int out_size, void* d_ws, size_t ws_size,
                              hipStream_t stream) {
  const float* pitch = (const float*)d_in[0];
  const float* amp   = (const float*)d_in[1];
  const float* y     = (const float*)d_in[2];
  const float* wt    = (const float*)d_in[3];
  const float* cw    = (const float*)d_in[4];
  const float* cb    = (const float*)d_in[5];
  float* out = (float*)d_out;

  int BT = in_sizes[2];   // B*T
  int T = BT / BB;        // 132300
  int NB1 = (T + SBASE - 1) / SBASE;  // 8269

  float* ws   = (float*)d_ws;
  float* sarr = ws;
  float* wtT  = ws + (size_t)BT;
  float* s1g  = ws + (size_t)BT + NWT * LWT;

  hipLaunchKernelGGL(scan_level0, dim3((NB1 + 255) / 256, BB), dim3(256), 0, stream,
                     pitch, sarr, s1g, T, NB1);
  hipLaunchKernelGGL(scan_upper, dim3(BB), dim3(1024), 0, stream, s1g, NB1);
  hipLaunchKernelGGL(transpose_wt, dim3((NWT * LWT + 255) / 256), dim3(256), 0, stream, wt, wtT);
  hipLaunchKernelGGL(fused_out, dim3((T + 63) / 64), dim3(256), 0, stream,
                     pitch, sarr, s1g, y, amp, wtT, cw, cb, out, T, NB1);
}